// Round 1
// baseline (149.308 us; speedup 1.0000x reference)
//
#include <hip/hip_runtime.h>

#define LEAK 0.2f
#define NROW 8192
#define KDIM 128
#define MAXD 128

// ---- workspace layout (bytes) ----
#define OF_FLAG  0x0ul
#define OF_CNT   0x1000ul     // 8192 * 4
#define OF_EL    0x9000ul     // 8192 * 4
#define OF_ER    0x11000ul    // 8192 * 4
#define OF_B0    0x19000ul    // 128 f32
#define OF_B1    0x19200ul
#define OF_B2    0x19400ul
#define OF_AW0   0x19600ul    // 256 f32
#define OF_AW1   0x19A00ul
#define OF_AW2   0x19E00ul    // 128 f32
#define OF_AB    0x1A000ul    // 3 f32
#define OF_W0B   0x1B000ul    // 16384 bf16
#define OF_W1B   0x23000ul
#define OF_W2B   0x2B000ul    // 8192 bf16
#define OF_XB    0x40000ul    // 8192*128 bf16 (2MB)  layer1 input; layer2 agg output
#define OF_HAF   0x240000ul   // 8192*128 f32 (4MB)   per-layer h (post leaky_relu)
#define OF_HB    0x640000ul   // 8192*128 bf16 (2MB)  layer1 agg output
#define OF_NBR   0x840000ul   // 8192*128 u16 (2MB)   neighbor lists

typedef __attribute__((ext_vector_type(8))) short bf16x8;
typedef __attribute__((ext_vector_type(4))) float f32x4;

__device__ __forceinline__ float b2f(unsigned short u) {
  return __uint_as_float(((unsigned)u) << 16);
}
__device__ __forceinline__ unsigned short f2b(float f) {
  unsigned u = __float_as_uint(f);
  unsigned r = (u + 0x7FFFu + ((u >> 16) & 1u)) >> 16;
  return (unsigned short)r;
}
__device__ __forceinline__ float ld_any(const void* p, long i, int isb) {
  return isb ? b2f(((const unsigned short*)p)[i]) : ((const float*)p)[i];
}

// ---- dtype probe: any nonzero low-16 bits in first 64KB of adj => bf16 ----
__global__ void k_detect(const unsigned* __restrict__ adj, int* __restrict__ flag) {
  __shared__ int s;
  if (threadIdx.x == 0) s = 0;
  __syncthreads();
  int any = 0;
  for (int i = threadIdx.x; i < 16384; i += blockDim.x)
    if (adj[i] & 0xFFFFu) any = 1;
  if (any) atomicOr(&s, 1);
  __syncthreads();
  if (threadIdx.x == 0) *flag = s;
}

// ---- convert all small tensors to canonical forms in ws ----
__global__ void k_convert(const void* x, const void* W0, const void* b0, const void* aW0, const void* ab0,
                          const void* W1, const void* b1, const void* aW1, const void* ab1,
                          const void* W2, const void* b2, const void* aW2, const void* ab2,
                          char* ws) {
  const int isb = *(const int*)(ws + OF_FLAG);
  long i = (long)blockIdx.x * blockDim.x + threadIdx.x;
  if (i < 1048576) { ((unsigned short*)(ws + OF_XB))[i] = f2b(ld_any(x, i, isb)); return; }
  i -= 1048576;
  if (i < 16384) { ((unsigned short*)(ws + OF_W0B))[i] = f2b(ld_any(W0, i, isb)); return; }
  i -= 16384;
  if (i < 16384) { ((unsigned short*)(ws + OF_W1B))[i] = f2b(ld_any(W1, i, isb)); return; }
  i -= 16384;
  if (i < 8192) { ((unsigned short*)(ws + OF_W2B))[i] = f2b(ld_any(W2, i, isb)); return; }
  i -= 8192;
  if (i < 128) { ((float*)(ws + OF_B0))[i] = ld_any(b0, i, isb); return; }
  i -= 128;
  if (i < 128) { ((float*)(ws + OF_B1))[i] = ld_any(b1, i, isb); return; }
  i -= 128;
  if (i < 64) { ((float*)(ws + OF_B2))[i] = ld_any(b2, i, isb); return; }
  i -= 64;
  if (i < 256) { ((float*)(ws + OF_AW0))[i] = ld_any(aW0, i, isb); return; }
  i -= 256;
  if (i < 256) { ((float*)(ws + OF_AW1))[i] = ld_any(aW1, i, isb); return; }
  i -= 256;
  if (i < 128) { ((float*)(ws + OF_AW2))[i] = ld_any(aW2, i, isb); return; }
  i -= 128;
  if (i < 1) { ((float*)(ws + OF_AB))[0] = ld_any(ab0, 0, isb); return; }
  i -= 1;
  if (i < 1) { ((float*)(ws + OF_AB))[1] = ld_any(ab1, 0, isb); return; }
  i -= 1;
  if (i < 1) { ((float*)(ws + OF_AB))[2] = ld_any(ab2, 0, isb); return; }
}

// ---- neighbor-list build: one wave per row, ballot-packed (deterministic) ----
__global__ __launch_bounds__(256) void k_nbrs(const void* __restrict__ adj, char* __restrict__ ws) {
  const int isb = *(const int*)(ws + OF_FLAG);
  int row = blockIdx.x * 4 + (threadIdx.x >> 6);
  int lane = threadIdx.x & 63;
  unsigned long long ltm = (1ull << lane) - 1ull;
  unsigned short* nb = (unsigned short*)(ws + OF_NBR) + (long)row * MAXD;
  int cnt = 0;
  if (isb) {
    const uint4* base = (const uint4*)((const char*)adj + (long)row * (NROW * 2));
    for (int t = 0; t < 16; ++t) {
      uint4 v = base[t * 64 + lane];
      unsigned u[4] = {v.x, v.y, v.z, v.w};
      int cb = t * 512 + lane * 8;
      #pragma unroll
      for (int q = 0; q < 4; ++q)
        #pragma unroll
        for (int k = 0; k < 2; ++k) {
          int nz = ((u[q] >> (16 * k)) & 0xFFFFu) != 0;
          unsigned long long m = __ballot(nz);
          if (nz) { int p = cnt + __popcll(m & ltm); if (p < MAXD) nb[p] = (unsigned short)(cb + q * 2 + k); }
          cnt += __popcll(m);
        }
    }
  } else {
    const uint4* base = (const uint4*)((const char*)adj + (long)row * (NROW * 4));
    for (int t = 0; t < 32; ++t) {
      uint4 v = base[t * 64 + lane];
      unsigned u[4] = {v.x, v.y, v.z, v.w};
      int cb = t * 256 + lane * 4;
      #pragma unroll
      for (int q = 0; q < 4; ++q) {
        int nz = u[q] != 0;
        unsigned long long m = __ballot(nz);
        if (nz) { int p = cnt + __popcll(m & ltm); if (p < MAXD) nb[p] = (unsigned short)(cb + q); }
        cnt += __popcll(m);
      }
    }
  }
  if (lane == 0) ((int*)(ws + OF_CNT))[row] = (cnt < MAXD ? cnt : MAXD);
}

// ---- h = leaky_relu(X @ W^T + b); X,W bf16 (K-contiguous), H f32 ----
template<int F>
__global__ __launch_bounds__(256) void k_gemm(const unsigned short* __restrict__ X,
                                              const unsigned short* __restrict__ W,
                                              const float* __restrict__ bias,
                                              float* __restrict__ H) {
  int wid = blockIdx.x * 4 + (threadIdx.x >> 6);
  constexpr int NFT = F / 16;
  int ti = wid / NFT, tf = wid % NFT;
  int lane = threadIdx.x & 63;
  int r = lane & 15;
  int k0 = (lane >> 4) * 8;
  const unsigned short* xp = X + (long)(ti * 16 + r) * KDIM + k0;
  const unsigned short* wp = W + (long)(tf * 16 + r) * KDIM + k0;
  f32x4 acc = {0.f, 0.f, 0.f, 0.f};
  #pragma unroll
  for (int kb = 0; kb < KDIM; kb += 32) {
    bf16x8 a = *(const bf16x8*)(xp + kb);
    bf16x8 b = *(const bf16x8*)(wp + kb);
    acc = __builtin_amdgcn_mfma_f32_16x16x32_bf16(a, b, acc, 0, 0, 0);
  }
  float bv = bias[tf * 16 + r];
  int orow = ti * 16 + (lane >> 4) * 4;
  #pragma unroll
  for (int j = 0; j < 4; ++j) {
    float v = acc[j] + bv;
    v = v > 0.f ? v : LEAK * v;
    H[(long)(orow + j) * F + tf * 16 + r] = v;
  }
}

// ---- el/er: two dot products per row ----
template<int F>
__global__ __launch_bounds__(256) void k_elr(const float* __restrict__ H,
                                             const float* __restrict__ aW,
                                             float* __restrict__ el, float* __restrict__ er) {
  int row = blockIdx.x * 4 + (threadIdx.x >> 6);
  int lane = threadIdx.x & 63;
  float sl = 0.f, sr = 0.f;
  #pragma unroll
  for (int d = lane; d < F; d += 64) {
    float hv = H[(long)row * F + d];
    sl += hv * aW[d];
    sr += hv * aW[F + d];
  }
  #pragma unroll
  for (int o = 32; o > 0; o >>= 1) { sl += __shfl_down(sl, o); sr += __shfl_down(sr, o); }
  if (lane == 0) { el[row] = sl; er[row] = sr; }
}

// ---- sparse masked-softmax aggregation + relu; OUTMODE 0: bf16 ws buf, 1: d_out per flag ----
template<int F, int OUTMODE>
__global__ __launch_bounds__(256) void k_agg(const float* __restrict__ H,
                                             const float* __restrict__ el,
                                             const float* __restrict__ er,
                                             const float* __restrict__ abp,
                                             const unsigned short* __restrict__ nbrs,
                                             const int* __restrict__ cnts,
                                             void* __restrict__ out,
                                             const int* __restrict__ flagp) {
  int row = blockIdx.x * 4 + (threadIdx.x >> 6);
  int lane = threadIdx.x & 63;
  int cnt = cnts[row];
  const unsigned short* nb = nbrs + (long)row * MAXD;
  float eli = el[row] + abp[0];
  float acc0 = 0.f, acc1 = 0.f, den = 0.f;
  for (int t0 = 0; t0 < cnt; t0 += 64) {
    int nrem = min(64, cnt - t0);
    int j = 0; float w = 0.f;
    if (lane < nrem) { j = nb[t0 + lane]; w = expf(eli + er[j]); }
    for (int t = 0; t < nrem; ++t) {
      float wt = __shfl(w, t);
      int jt = __shfl(j, t);
      den += wt;
      if (F == 128) {
        float2 hv = *(const float2*)(H + (long)jt * 128 + lane * 2);
        acc0 += wt * hv.x;
        acc1 += wt * hv.y;
      } else {
        acc0 += wt * H[(long)jt * F + lane];
      }
    }
  }
  float inv = (den > 0.f) ? 1.f / den : 0.f;
  if (F == 128) {
    float v0 = acc0 * inv; v0 = v0 > 0.f ? v0 : 0.f;
    float v1 = acc1 * inv; v1 = v1 > 0.f ? v1 : 0.f;
    unsigned short* o = (unsigned short*)out;
    o[(long)row * 128 + lane * 2]     = f2b(v0);
    o[(long)row * 128 + lane * 2 + 1] = f2b(v1);
  } else {
    float v0 = acc0 * inv; v0 = v0 > 0.f ? v0 : 0.f;
    if (OUTMODE == 1) {
      if (*flagp) ((unsigned short*)out)[(long)row * F + lane] = f2b(v0);
      else        ((float*)out)[(long)row * F + lane] = v0;
    } else {
      ((unsigned short*)out)[(long)row * F + lane] = f2b(v0);
    }
  }
}

extern "C" void kernel_launch(void* const* d_in, const int* in_sizes, int n_in,
                              void* d_out, int out_size, void* d_ws, size_t ws_size,
                              hipStream_t stream) {
  char* ws = (char*)d_ws;
  const void* x   = d_in[0];
  const void* adj = d_in[1];
  const void* W0 = d_in[2];  const void* b0 = d_in[3];  const void* aW0 = d_in[4];  const void* ab0 = d_in[5];
  const void* W1 = d_in[6];  const void* b1 = d_in[7];  const void* aW1 = d_in[8];  const void* ab1 = d_in[9];
  const void* W2 = d_in[10]; const void* b2 = d_in[11]; const void* aW2 = d_in[12]; const void* ab2 = d_in[13];

  int* flag = (int*)(ws + OF_FLAG);
  k_detect<<<1, 256, 0, stream>>>((const unsigned*)adj, flag);
  k_convert<<<4260, 256, 0, stream>>>(x, W0, b0, aW0, ab0, W1, b1, aW1, ab1, W2, b2, aW2, ab2, ws);
  k_nbrs<<<2048, 256, 0, stream>>>(adj, ws);

  const unsigned short* XB = (const unsigned short*)(ws + OF_XB);
  unsigned short* XBW = (unsigned short*)(ws + OF_XB);
  float* HAF = (float*)(ws + OF_HAF);
  unsigned short* HB = (unsigned short*)(ws + OF_HB);
  float* EL = (float*)(ws + OF_EL);
  float* ER = (float*)(ws + OF_ER);
  const unsigned short* NB = (const unsigned short*)(ws + OF_NBR);
  const int* CNT = (const int*)(ws + OF_CNT);
  const float* ABF = (const float*)(ws + OF_AB);

  // ---- layer 1 ----
  k_gemm<128><<<1024, 256, 0, stream>>>(XB, (const unsigned short*)(ws + OF_W0B), (const float*)(ws + OF_B0), HAF);
  k_elr<128><<<2048, 256, 0, stream>>>(HAF, (const float*)(ws + OF_AW0), EL, ER);
  k_agg<128, 0><<<2048, 256, 0, stream>>>(HAF, EL, ER, ABF + 0, NB, CNT, HB, flag);
  // ---- layer 2 ----
  k_gemm<128><<<1024, 256, 0, stream>>>(HB, (const unsigned short*)(ws + OF_W1B), (const float*)(ws + OF_B1), HAF);
  k_elr<128><<<2048, 256, 0, stream>>>(HAF, (const float*)(ws + OF_AW1), EL, ER);
  k_agg<128, 0><<<2048, 256, 0, stream>>>(HAF, EL, ER, ABF + 1, NB, CNT, XBW, flag);
  // ---- layer 3 ----
  k_gemm<64><<<512, 256, 0, stream>>>(XBW, (const unsigned short*)(ws + OF_W2B), (const float*)(ws + OF_B2), HAF);
  k_elr<64><<<2048, 256, 0, stream>>>(HAF, (const float*)(ws + OF_AW2), EL, ER);
  k_agg<64, 1><<<2048, 256, 0, stream>>>(HAF, EL, ER, ABF + 2, NB, CNT, d_out, flag);
}

// Round 3
// 138.620 us; speedup vs baseline: 1.0771x; 1.0771x over previous
//
#include <hip/hip_runtime.h>

#define LEAK 0.2f
#define NROW 8192
#define KDIM 128
#define MAXD 128

// ---- workspace layout (bytes) ----
#define OF_FLAG  0x00000ul    // 4
#define OF_CNT   0x01000ul    // 8192*4
#define OF_EL    0x09000ul    // 8192*4
#define OF_ER    0x11000ul    // 8192*4
#define OF_W0B   0x19000ul    // 16384 bf16
#define OF_W1B   0x21000ul    // 16384 bf16
#define OF_W2B   0x29000ul    // 8192 bf16
#define OF_B0    0x2D000ul    // 128 f32
#define OF_B1    0x2D200ul    // 128 f32
#define OF_B2    0x2D400ul    // 64 f32
#define OF_AW0   0x2D600ul    // 256 f32
#define OF_AW1   0x2DA00ul    // 256 f32
#define OF_AW2   0x2DE00ul    // 128 f32
#define OF_AB    0x2E000ul    // 3 f32
#define OF_XB    0x040000ul   // 8192*128 bf16 (2MB) converted x
#define OF_HB    0x240000ul   // 8192*128 bf16 (2MB) per-layer h
#define OF_AG1   0x440000ul   // 8192*128 bf16 (2MB)
#define OF_AG2   0x640000ul   // 8192*128 bf16 (2MB)
#define OF_NBR   0x840000ul   // 8192*128 u16  (2MB)

typedef __attribute__((ext_vector_type(8))) short bf16x8;
typedef __attribute__((ext_vector_type(4))) float f32x4;

__device__ __forceinline__ float b2f(unsigned short u) {
  return __uint_as_float(((unsigned)u) << 16);
}
__device__ __forceinline__ unsigned short f2b(float f) {
  unsigned u = __float_as_uint(f);
  unsigned r = (u + 0x7FFFu + ((u >> 16) & 1u)) >> 16;
  return (unsigned short)r;
}
__device__ __forceinline__ float ld_any(const void* p, long i, int isb) {
  return isb ? b2f(((const unsigned short*)p)[i]) : ((const float*)p)[i];
}

// ---- dtype probe: any nonzero low-16 bits in first 64KB of adj => bf16 ----
// (f32 0.0/1.0 dwords have zero low-16 bits; bf16 pairs put 0x3F80 in low half)
__global__ void k_detect(const unsigned* __restrict__ adj, int* __restrict__ flag) {
  __shared__ int s;
  if (threadIdx.x == 0) s = 0;
  __syncthreads();
  int any = 0;
  for (int i = threadIdx.x; i < 16384; i += blockDim.x)
    if (adj[i] & 0xFFFFu) any = 1;
  if (any) atomicOr(&s, 1);
  __syncthreads();
  if (threadIdx.x == 0) *flag = s;
}

// ---- convert all small tensors to canonical forms in ws ----
__global__ void k_convert(const void* x, const void* W0, const void* b0, const void* aW0, const void* ab0,
                          const void* W1, const void* b1, const void* aW1, const void* ab1,
                          const void* W2, const void* b2, const void* aW2, const void* ab2,
                          char* ws) {
  const int isb = *(const int*)(ws + OF_FLAG);
  long i = (long)blockIdx.x * blockDim.x + threadIdx.x;
  if (i < 1048576) { ((unsigned short*)(ws + OF_XB))[i] = f2b(ld_any(x, i, isb)); return; }
  i -= 1048576;
  if (i < 16384) { ((unsigned short*)(ws + OF_W0B))[i] = f2b(ld_any(W0, i, isb)); return; }
  i -= 16384;
  if (i < 16384) { ((unsigned short*)(ws + OF_W1B))[i] = f2b(ld_any(W1, i, isb)); return; }
  i -= 16384;
  if (i < 8192) { ((unsigned short*)(ws + OF_W2B))[i] = f2b(ld_any(W2, i, isb)); return; }
  i -= 8192;
  if (i < 128) { ((float*)(ws + OF_B0))[i] = ld_any(b0, i, isb); return; }
  i -= 128;
  if (i < 128) { ((float*)(ws + OF_B1))[i] = ld_any(b1, i, isb); return; }
  i -= 128;
  if (i < 64) { ((float*)(ws + OF_B2))[i] = ld_any(b2, i, isb); return; }
  i -= 64;
  if (i < 256) { ((float*)(ws + OF_AW0))[i] = ld_any(aW0, i, isb); return; }
  i -= 256;
  if (i < 256) { ((float*)(ws + OF_AW1))[i] = ld_any(aW1, i, isb); return; }
  i -= 256;
  if (i < 128) { ((float*)(ws + OF_AW2))[i] = ld_any(aW2, i, isb); return; }
  i -= 128;
  if (i < 1) { ((float*)(ws + OF_AB))[0] = ld_any(ab0, 0, isb); return; }
  i -= 1;
  if (i < 1) { ((float*)(ws + OF_AB))[1] = ld_any(ab1, 0, isb); return; }
  i -= 1;
  if (i < 1) { ((float*)(ws + OF_AB))[2] = ld_any(ab2, 0, isb); return; }
}

// ---- neighbor-list build: one wave per row, ballot-packed (deterministic) ----
__global__ __launch_bounds__(256) void k_nbrs(const void* __restrict__ adj, char* __restrict__ ws) {
  const int isb = *(const int*)(ws + OF_FLAG);
  int row = blockIdx.x * 4 + (threadIdx.x >> 6);
  int lane = threadIdx.x & 63;
  unsigned long long ltm = (1ull << lane) - 1ull;
  unsigned short* nb = (unsigned short*)(ws + OF_NBR) + (long)row * MAXD;
  int cnt = 0;
  if (isb) {
    const uint4* base = (const uint4*)((const char*)adj + (long)row * (NROW * 2));
    for (int t = 0; t < 16; ++t) {
      uint4 v = base[t * 64 + lane];
      unsigned u[4] = {v.x, v.y, v.z, v.w};
      int cb = t * 512 + lane * 8;
      #pragma unroll
      for (int q = 0; q < 4; ++q)
        #pragma unroll
        for (int k = 0; k < 2; ++k) {
          int nz = ((u[q] >> (16 * k)) & 0xFFFFu) != 0;
          unsigned long long m = __ballot(nz);
          if (nz) { int p = cnt + __popcll(m & ltm); if (p < MAXD) nb[p] = (unsigned short)(cb + q * 2 + k); }
          cnt += __popcll(m);
        }
    }
  } else {
    const uint4* base = (const uint4*)((const char*)adj + (long)row * (NROW * 4));
    for (int t = 0; t < 32; ++t) {
      uint4 v = base[t * 64 + lane];
      unsigned u[4] = {v.x, v.y, v.z, v.w};
      int cb = t * 256 + lane * 4;
      #pragma unroll
      for (int q = 0; q < 4; ++q) {
        int nz = u[q] != 0;
        unsigned long long m = __ballot(nz);
        if (nz) { int p = cnt + __popcll(m & ltm); if (p < MAXD) nb[p] = (unsigned short)(cb + q); }
        cnt += __popcll(m);
      }
    }
  }
  if (lane == 0) ((int*)(ws + OF_CNT))[row] = (cnt < MAXD ? cnt : MAXD);
}

// ---- h = leaky_relu(X @ W^T + b) -> bf16 HB; el/er fused (deterministic) ----
// block: F/16 waves; wave w owns feature tile w; 16 rows per block; grid 512
template<int F>
__global__ __launch_bounds__(F / 16 * 64) void k_gemm_elr(
    const unsigned short* __restrict__ X, const unsigned short* __restrict__ W,
    const float* __restrict__ bia, const float* __restrict__ aW,
    unsigned short* __restrict__ HB, float* __restrict__ EL, float* __restrict__ ER) {
  constexpr int NW = F / 16;
  __shared__ float sEL[NW][16], sER[NW][16];
  int w = threadIdx.x >> 6;
  int lane = threadIdx.x & 63;
  int row0 = blockIdx.x * 16;
  int r = lane & 15;
  int k0 = (lane >> 4) * 8;
  const unsigned short* xp = X + (long)(row0 + r) * KDIM + k0;
  const unsigned short* wp = W + (long)(w * 16 + r) * KDIM + k0;
  f32x4 acc = {0.f, 0.f, 0.f, 0.f};
  #pragma unroll
  for (int kb = 0; kb < KDIM; kb += 32) {
    bf16x8 a = *(const bf16x8*)(xp + kb);
    bf16x8 b = *(const bf16x8*)(wp + kb);
    acc = __builtin_amdgcn_mfma_f32_16x16x32_bf16(a, b, acc, 0, 0, 0);
  }
  int colg = w * 16 + r;
  float bb = bia[colg];
  float al = aW[colg];
  float ar = aW[F + colg];
  #pragma unroll
  for (int j = 0; j < 4; ++j) {
    int rloc = (lane >> 4) * 4 + j;
    float v = acc[j] + bb;
    v = v > 0.f ? v : LEAK * v;
    HB[(long)(row0 + rloc) * F + colg] = f2b(v);
    float tl = v * al, tr = v * ar;
    #pragma unroll
    for (int m = 1; m < 16; m <<= 1) { tl += __shfl_xor(tl, m); tr += __shfl_xor(tr, m); }
    if (r == 0) { sEL[w][rloc] = tl; sER[w][rloc] = tr; }
  }
  __syncthreads();
  if (threadIdx.x < 16) {
    float sl = 0.f, sr = 0.f;
    #pragma unroll
    for (int q = 0; q < NW; ++q) { sl += sEL[q][threadIdx.x]; sr += sER[q][threadIdx.x]; }
    EL[row0 + threadIdx.x] = sl;
    ER[row0 + threadIdx.x] = sr;
  }
}

// ---- sparse masked-softmax aggregation + relu ----
// OUTMODE 0: bf16 ws buffer.  OUTMODE 1: d_out, f32 or bf16 per flag.
template<int F, int OUTMODE>
__global__ __launch_bounds__(256) void k_agg(const unsigned short* __restrict__ HB,
                                             const float* __restrict__ EL,
                                             const float* __restrict__ ER,
                                             const float* __restrict__ abp,
                                             const unsigned short* __restrict__ nbr,
                                             const int* __restrict__ cnts,
                                             void* __restrict__ out,
                                             const int* __restrict__ flagp) {
  int row = blockIdx.x * 4 + (threadIdx.x >> 6);
  int lane = threadIdx.x & 63;
  int cnt = cnts[row];
  const unsigned short* nb = nbr + (long)row * MAXD;
  float eli = EL[row] + abp[0];
  float acc0 = 0.f, acc1 = 0.f, den = 0.f;
  for (int t0 = 0; t0 < cnt; t0 += 64) {
    int nrem = min(64, cnt - t0);
    int j = 0; float wv = 0.f;
    if (lane < nrem) { j = nb[t0 + lane]; wv = expf(eli + ER[j]); }
    for (int t = 0; t < nrem; ++t) {
      float wt = __shfl(wv, t);
      int jt = __shfl(j, t);
      den += wt;
      if (F == 128) {
        unsigned hv = ((const unsigned*)HB)[(long)jt * 64 + lane];
        acc0 += wt * b2f((unsigned short)(hv & 0xFFFFu));
        acc1 += wt * b2f((unsigned short)(hv >> 16));
      } else {
        acc0 += wt * b2f(HB[(long)jt * F + lane]);
      }
    }
  }
  float inv = (den > 0.f) ? 1.f / den : 0.f;
  if (F == 128) {
    float v0 = acc0 * inv; v0 = v0 > 0.f ? v0 : 0.f;
    float v1 = acc1 * inv; v1 = v1 > 0.f ? v1 : 0.f;
    ((unsigned*)out)[(long)row * 64 + lane] = ((unsigned)f2b(v1) << 16) | (unsigned)f2b(v0);
  } else {
    float v0 = acc0 * inv; v0 = v0 > 0.f ? v0 : 0.f;
    if (OUTMODE == 1) {
      if (*flagp) ((unsigned short*)out)[(long)row * F + lane] = f2b(v0);
      else        ((float*)out)[(long)row * F + lane] = v0;
    } else {
      ((unsigned short*)out)[(long)row * F + lane] = f2b(v0);
    }
  }
}

extern "C" void kernel_launch(void* const* d_in, const int* in_sizes, int n_in,
                              void* d_out, int out_size, void* d_ws, size_t ws_size,
                              hipStream_t stream) {
  char* ws = (char*)d_ws;
  const void* x   = d_in[0];
  const void* adj = d_in[1];
  const void* W0 = d_in[2];  const void* b0 = d_in[3];  const void* aW0 = d_in[4];  const void* ab0 = d_in[5];
  const void* W1 = d_in[6];  const void* b1 = d_in[7];  const void* aW1 = d_in[8];  const void* ab1 = d_in[9];
  const void* W2 = d_in[10]; const void* b2 = d_in[11]; const void* aW2 = d_in[12]; const void* ab2 = d_in[13];

  int* flag = (int*)(ws + OF_FLAG);
  k_detect<<<1, 256, 0, stream>>>((const unsigned*)adj, flag);
  k_convert<<<4260, 256, 0, stream>>>(x, W0, b0, aW0, ab0, W1, b1, aW1, ab1, W2, b2, aW2, ab2, ws);
  k_nbrs<<<2048, 256, 0, stream>>>(adj, ws);

  const unsigned short* XB = (const unsigned short*)(ws + OF_XB);
  unsigned short* HB  = (unsigned short*)(ws + OF_HB);
  unsigned short* AG1 = (unsigned short*)(ws + OF_AG1);
  unsigned short* AG2 = (unsigned short*)(ws + OF_AG2);
  const unsigned short* NBR = (const unsigned short*)(ws + OF_NBR);
  const int* CNT = (const int*)(ws + OF_CNT);
  float* EL = (float*)(ws + OF_EL);
  float* ER = (float*)(ws + OF_ER);
  const float* ABF = (const float*)(ws + OF_AB);

  // ---- layer 1 ----
  k_gemm_elr<128><<<512, 512, 0, stream>>>(XB, (const unsigned short*)(ws + OF_W0B),
                                           (const float*)(ws + OF_B0), (const float*)(ws + OF_AW0), HB, EL, ER);
  k_agg<128, 0><<<2048, 256, 0, stream>>>(HB, EL, ER, ABF + 0, NBR, CNT, AG1, flag);
  // ---- layer 2 ----
  k_gemm_elr<128><<<512, 512, 0, stream>>>(AG1, (const unsigned short*)(ws + OF_W1B),
                                           (const float*)(ws + OF_B1), (const float*)(ws + OF_AW1), HB, EL, ER);
  k_agg<128, 0><<<2048, 256, 0, stream>>>(HB, EL, ER, ABF + 1, NBR, CNT, AG2, flag);
  // ---- layer 3 ----
  k_gemm_elr<64><<<512, 256, 0, stream>>>(AG2, (const unsigned short*)(ws + OF_W2B),
                                          (const float*)(ws + OF_B2), (const float*)(ws + OF_AW2), HB, EL, ER);
  k_agg<64, 1><<<2048, 256, 0, stream>>>(HB, EL, ER, ABF + 2, NBR, CNT, d_out, flag);
}

// Round 4
// 115.539 us; speedup vs baseline: 1.2923x; 1.1998x over previous
//
#include <hip/hip_runtime.h>

#define LEAK 0.2f
#define NROW 8192
#define KDIM 128
#define MAXD 128

// ---- workspace layout (bytes) ----
#define OF_FLAG  0x00000ul    // 4
#define OF_CNT   0x01000ul    // 8192*4
#define OF_EL    0x09000ul    // 8192*4
#define OF_ER    0x11000ul    // 8192*4
#define OF_HB    0x020000ul   // 8192*128 bf16 (2MB) per-layer h
#define OF_AG1   0x220000ul   // 8192*128 bf16 (2MB)
#define OF_AG2   0x420000ul   // 8192*128 bf16 (2MB)
#define OF_NBR   0x620000ul   // 8192*128 u16  (2MB)

typedef __attribute__((ext_vector_type(8))) short bf16x8;
typedef __attribute__((ext_vector_type(4))) float f32x4;

__device__ __forceinline__ float b2f(unsigned short u) {
  return __uint_as_float(((unsigned)u) << 16);
}
__device__ __forceinline__ unsigned short f2b(float f) {
  unsigned u = __float_as_uint(f);
  unsigned r = (u + 0x7FFFu + ((u >> 16) & 1u)) >> 16;
  return (unsigned short)r;
}
__device__ __forceinline__ float ld_any(const void* p, long i, int isb) {
  return isb ? b2f(((const unsigned short*)p)[i]) : ((const float*)p)[i];
}

// ---- dtype probe: any nonzero low-16 bits in first 64KB of adj => bf16 ----
__global__ __launch_bounds__(1024) void k_detect(const uint4* __restrict__ adj4, int* __restrict__ flag) {
  __shared__ int s;
  if (threadIdx.x == 0) s = 0;
  __syncthreads();
  int any = 0;
  #pragma unroll
  for (int i = 0; i < 4; ++i) {
    uint4 v = adj4[threadIdx.x + i * 1024];
    if ((v.x | v.y | v.z | v.w) & 0xFFFFu) any = 1;
  }
  if (any) atomicOr(&s, 1);
  __syncthreads();
  if (threadIdx.x == 0) *flag = s;
}

// ---- load 8 consecutive elements as bf16x8; MODE 0: ws bf16, 1: raw per isb ----
template<int XMODE>
__device__ __forceinline__ bf16x8 load_frag(const void* X, long off, int isb) {
  if (XMODE == 0 || isb) {
    return *(const bf16x8*)((const unsigned short*)X + off);
  } else {
    const float* f = (const float*)X + off;
    float4 p0 = *(const float4*)f;
    float4 p1 = *(const float4*)(f + 4);
    bf16x8 o;
    ((unsigned short*)&o)[0] = f2b(p0.x); ((unsigned short*)&o)[1] = f2b(p0.y);
    ((unsigned short*)&o)[2] = f2b(p0.z); ((unsigned short*)&o)[3] = f2b(p0.w);
    ((unsigned short*)&o)[4] = f2b(p1.x); ((unsigned short*)&o)[5] = f2b(p1.y);
    ((unsigned short*)&o)[6] = f2b(p1.z); ((unsigned short*)&o)[7] = f2b(p1.w);
    return o;
  }
}

// ---- h = leaky_relu(X @ W^T + b) -> bf16 HB; fused el/er (deterministic) ----
template<int F, int XMODE>
__device__ __forceinline__ void gemm_body(const void* X, const void* W,
    const void* bia, const void* aW, unsigned short* HB, float* EL, float* ER,
    int isb, int row0) {
  constexpr int NW = F / 16;
  __shared__ float sEL[NW][16], sER[NW][16];
  int w = threadIdx.x >> 6;
  int lane = threadIdx.x & 63;
  int r = lane & 15;
  int k0 = (lane >> 4) * 8;
  long xoff = (long)(row0 + r) * KDIM + k0;
  long woff = (long)(w * 16 + r) * KDIM + k0;
  f32x4 acc = {0.f, 0.f, 0.f, 0.f};
  #pragma unroll
  for (int kb = 0; kb < KDIM; kb += 32) {
    bf16x8 a = load_frag<XMODE>(X, xoff + kb, isb);
    bf16x8 b = load_frag<1>(W, woff + kb, isb);
    acc = __builtin_amdgcn_mfma_f32_16x16x32_bf16(a, b, acc, 0, 0, 0);
  }
  int colg = w * 16 + r;
  float bb = ld_any(bia, colg, isb);
  float al = ld_any(aW, colg, isb);
  float ar = ld_any(aW, F + colg, isb);
  #pragma unroll
  for (int j = 0; j < 4; ++j) {
    int rloc = (lane >> 4) * 4 + j;
    float v = acc[j] + bb;
    v = v > 0.f ? v : LEAK * v;
    HB[(long)(row0 + rloc) * F + colg] = f2b(v);
    float tl = v * al, tr = v * ar;
    #pragma unroll
    for (int m = 1; m < 16; m <<= 1) { tl += __shfl_xor(tl, m); tr += __shfl_xor(tr, m); }
    if (r == 0) { sEL[w][rloc] = tl; sER[w][rloc] = tr; }
  }
  __syncthreads();
  if (threadIdx.x < 16) {
    float sl = 0.f, sr = 0.f;
    #pragma unroll
    for (int q = 0; q < NW; ++q) { sl += sEL[q][threadIdx.x]; sr += sER[q][threadIdx.x]; }
    EL[row0 + threadIdx.x] = sl;
    ER[row0 + threadIdx.x] = sr;
  }
}

// ---- neighbor-list build for one row (one wave), ballot-packed ----
__device__ __forceinline__ void nbrs_body(const void* adj, char* ws, int isb, int row, int lane) {
  unsigned long long ltm = (1ull << lane) - 1ull;
  unsigned short* nb = (unsigned short*)(ws + OF_NBR) + (long)row * MAXD;
  int cnt = 0;
  if (isb) {
    const uint4* base = (const uint4*)((const char*)adj + (long)row * (NROW * 2));
    for (int t = 0; t < 16; ++t) {
      uint4 v = base[t * 64 + lane];
      unsigned u[4] = {v.x, v.y, v.z, v.w};
      int cb = t * 512 + lane * 8;
      #pragma unroll
      for (int q = 0; q < 4; ++q)
        #pragma unroll
        for (int k = 0; k < 2; ++k) {
          int nz = ((u[q] >> (16 * k)) & 0xFFFFu) != 0;
          unsigned long long m = __ballot(nz);
          if (nz) { int p = cnt + __popcll(m & ltm); if (p < MAXD) nb[p] = (unsigned short)(cb + q * 2 + k); }
          cnt += __popcll(m);
        }
    }
  } else {
    const uint4* base = (const uint4*)((const char*)adj + (long)row * (NROW * 4));
    for (int t = 0; t < 32; ++t) {
      uint4 v = base[t * 64 + lane];
      unsigned u[4] = {v.x, v.y, v.z, v.w};
      int cb = t * 256 + lane * 4;
      #pragma unroll
      for (int q = 0; q < 4; ++q) {
        int nz = u[q] != 0;
        unsigned long long m = __ballot(nz);
        if (nz) { int p = cnt + __popcll(m & ltm); if (p < MAXD) nb[p] = (unsigned short)(cb + q); }
        cnt += __popcll(m);
      }
    }
  }
  if (lane == 0) ((int*)(ws + OF_CNT))[row] = (cnt < MAXD ? cnt : MAXD);
}

// ---- FAT: blocks [0,1024) build neighbor lists; blocks [1024,1536) do layer-1 gemm ----
__global__ __launch_bounds__(512) void k_fat(const void* __restrict__ adj, const void* __restrict__ x,
                                             const void* __restrict__ W0, const void* __restrict__ b0,
                                             const void* __restrict__ aW0, char* __restrict__ ws) {
  const int isb = *(const int*)(ws + OF_FLAG);
  if (blockIdx.x < 1024) {
    int row = blockIdx.x * 8 + (threadIdx.x >> 6);
    nbrs_body(adj, ws, isb, row, threadIdx.x & 63);
  } else {
    gemm_body<128, 1>(x, W0, b0, aW0,
                      (unsigned short*)(ws + OF_HB), (float*)(ws + OF_EL), (float*)(ws + OF_ER),
                      isb, (blockIdx.x - 1024) * 16);
  }
}

template<int F, int XMODE>
__global__ __launch_bounds__(F / 16 * 64) void k_gemm_elr(
    const void* __restrict__ X, const void* __restrict__ W,
    const void* __restrict__ bia, const void* __restrict__ aW,
    unsigned short* __restrict__ HB, float* __restrict__ EL, float* __restrict__ ER,
    const int* __restrict__ flagp) {
  gemm_body<F, XMODE>(X, W, bia, aW, HB, EL, ER, *flagp, blockIdx.x * 16);
}

// ---- sparse masked-softmax aggregation + relu, 4-way unrolled gather ----
// OUTMODE 0: bf16 ws buffer.  OUTMODE 1: d_out, f32 or bf16 per flag.
template<int F, int OUTMODE>
__global__ __launch_bounds__(256) void k_agg(const unsigned short* __restrict__ HB,
                                             const float* __restrict__ EL,
                                             const float* __restrict__ ER,
                                             const void* __restrict__ abp,
                                             const unsigned short* __restrict__ nbr,
                                             const int* __restrict__ cnts,
                                             void* __restrict__ out,
                                             const int* __restrict__ flagp) {
  int row = blockIdx.x * 4 + (threadIdx.x >> 6);
  int lane = threadIdx.x & 63;
  int cnt = cnts[row];
  const unsigned short* nb = nbr + (long)row * MAXD;
  int isb = *flagp;
  float eli = EL[row] + ld_any(abp, 0, isb);
  const unsigned* HBU = (const unsigned*)HB;
  float acc0 = 0.f, acc1 = 0.f, den = 0.f;
  for (int t0 = 0; t0 < cnt; t0 += 64) {
    int nrem = min(64, cnt - t0);
    int j = 0; float wv = 0.f;
    if (lane < nrem) { j = nb[t0 + lane]; wv = expf(eli + ER[j]); }
    int t = 0;
    for (; t + 4 <= nrem; t += 4) {
      float w0 = __shfl(wv, t),     w1 = __shfl(wv, t + 1);
      float w2 = __shfl(wv, t + 2), w3 = __shfl(wv, t + 3);
      int j0 = __shfl(j, t),     j1 = __shfl(j, t + 1);
      int j2 = __shfl(j, t + 2), j3 = __shfl(j, t + 3);
      den += (w0 + w1) + (w2 + w3);
      if (F == 128) {
        unsigned h0 = HBU[(long)j0 * 64 + lane];
        unsigned h1 = HBU[(long)j1 * 64 + lane];
        unsigned h2 = HBU[(long)j2 * 64 + lane];
        unsigned h3 = HBU[(long)j3 * 64 + lane];
        acc0 += w0 * b2f((unsigned short)(h0 & 0xFFFFu)) + w1 * b2f((unsigned short)(h1 & 0xFFFFu))
              + w2 * b2f((unsigned short)(h2 & 0xFFFFu)) + w3 * b2f((unsigned short)(h3 & 0xFFFFu));
        acc1 += w0 * b2f((unsigned short)(h0 >> 16)) + w1 * b2f((unsigned short)(h1 >> 16))
              + w2 * b2f((unsigned short)(h2 >> 16)) + w3 * b2f((unsigned short)(h3 >> 16));
      } else {
        float h0 = b2f(HB[(long)j0 * 64 + lane]);
        float h1 = b2f(HB[(long)j1 * 64 + lane]);
        float h2 = b2f(HB[(long)j2 * 64 + lane]);
        float h3 = b2f(HB[(long)j3 * 64 + lane]);
        acc0 += w0 * h0 + w1 * h1 + w2 * h2 + w3 * h3;
      }
    }
    for (; t < nrem; ++t) {
      float wt = __shfl(wv, t);
      int jt = __shfl(j, t);
      den += wt;
      if (F == 128) {
        unsigned hv = HBU[(long)jt * 64 + lane];
        acc0 += wt * b2f((unsigned short)(hv & 0xFFFFu));
        acc1 += wt * b2f((unsigned short)(hv >> 16));
      } else {
        acc0 += wt * b2f(HB[(long)jt * 64 + lane]);
      }
    }
  }
  float inv = (den > 0.f) ? 1.f / den : 0.f;
  if (F == 128) {
    float v0 = acc0 * inv; v0 = v0 > 0.f ? v0 : 0.f;
    float v1 = acc1 * inv; v1 = v1 > 0.f ? v1 : 0.f;
    ((unsigned*)out)[(long)row * 64 + lane] = ((unsigned)f2b(v1) << 16) | (unsigned)f2b(v0);
  } else {
    float v0 = acc0 * inv; v0 = v0 > 0.f ? v0 : 0.f;
    if (OUTMODE == 1) {
      if (isb) ((unsigned short*)out)[(long)row * F + lane] = f2b(v0);
      else     ((float*)out)[(long)row * F + lane] = v0;
    } else {
      ((unsigned short*)out)[(long)row * F + lane] = f2b(v0);
    }
  }
}

extern "C" void kernel_launch(void* const* d_in, const int* in_sizes, int n_in,
                              void* d_out, int out_size, void* d_ws, size_t ws_size,
                              hipStream_t stream) {
  char* ws = (char*)d_ws;
  const void* x   = d_in[0];
  const void* adj = d_in[1];
  const void* W0 = d_in[2];  const void* b0 = d_in[3];  const void* aW0 = d_in[4];  const void* ab0 = d_in[5];
  const void* W1 = d_in[6];  const void* b1 = d_in[7];  const void* aW1 = d_in[8];  const void* ab1 = d_in[9];
  const void* W2 = d_in[10]; const void* b2 = d_in[11]; const void* aW2 = d_in[12]; const void* ab2 = d_in[13];

  int* flag = (int*)(ws + OF_FLAG);
  unsigned short* HB  = (unsigned short*)(ws + OF_HB);
  unsigned short* AG1 = (unsigned short*)(ws + OF_AG1);
  unsigned short* AG2 = (unsigned short*)(ws + OF_AG2);
  const unsigned short* NBR = (const unsigned short*)(ws + OF_NBR);
  const int* CNT = (const int*)(ws + OF_CNT);
  float* EL = (float*)(ws + OF_EL);
  float* ER = (float*)(ws + OF_ER);

  k_detect<<<1, 1024, 0, stream>>>((const uint4*)adj, flag);
  // nbrs (blocks 0..1023)  ||  layer-1 gemm+elr (blocks 1024..1535)
  k_fat<<<1536, 512, 0, stream>>>(adj, x, W0, b0, aW0, ws);
  k_agg<128, 0><<<2048, 256, 0, stream>>>(HB, EL, ER, ab0, NBR, CNT, AG1, flag);
  // ---- layer 2 ----
  k_gemm_elr<128, 0><<<512, 512, 0, stream>>>(AG1, W1, b1, aW1, HB, EL, ER, flag);
  k_agg<128, 0><<<2048, 256, 0, stream>>>(HB, EL, ER, ab1, NBR, CNT, AG2, flag);
  // ---- layer 3 ----
  k_gemm_elr<64, 0><<<512, 256, 0, stream>>>(AG2, W2, b2, aW2, HB, EL, ER, flag);
  k_agg<64, 1><<<2048, 256, 0, stream>>>(HB, EL, ER, ab2, NBR, CNT, d_out, flag);
}